// Round 7
// baseline (310.573 us; speedup 1.0000x reference)
//
#include <hip/hip_runtime.h>
#include <cstdint>
#include <cstddef>

typedef __bf16 bf16_t;
typedef __bf16 bf16x8 __attribute__((ext_vector_type(8)));
typedef __bf16 bf16x4 __attribute__((ext_vector_type(4)));
typedef _Float16 f16_t;
typedef _Float16 f16x4 __attribute__((ext_vector_type(4)));
typedef float f32x4 __attribute__((ext_vector_type(4)));

constexpr int BB = 2, SS = 2048, DD = 1024, HH = 16, HDIM = 64;
constexpr int BS = BB * SS;  // 4096
constexpr float LOG2E = 1.4426950408889634f;

// async global->LDS, 16B per lane; LDS dest is wave-uniform base + lane*16
__device__ __forceinline__ void glds16(const void* g, void* l) {
  __builtin_amdgcn_global_load_lds((const __attribute__((address_space(1))) void*)g,
                                   (__attribute__((address_space(3))) void*)l, 16, 0, 0);
}

// ---------------- elementwise fp32 -> bf16 ----------------
__global__ void convert_x(const float* __restrict__ src, bf16_t* __restrict__ dst, int n4) {
  int i = blockIdx.x * blockDim.x + threadIdx.x;
  if (i >= n4) return;
  float4 v = ((const float4*)src)[i];
  union { bf16_t h[4]; uint2 u; } o;
  o.h[0] = (bf16_t)v.x; o.h[1] = (bf16_t)v.y; o.h[2] = (bf16_t)v.z; o.h[3] = (bf16_t)v.w;
  ((uint2*)dst)[i] = o.u;
}

// ---------------- 1024x1024 transpose + convert (LDS tiled) ----------------
__global__ void transpose_convert(const float* __restrict__ wq, const float* __restrict__ wk,
                                  const float* __restrict__ wv, const float* __restrict__ wo,
                                  bf16_t* __restrict__ wqkv_t, bf16_t* __restrict__ wo_t) {
  int which = blockIdx.z;
  const float* src = (which == 0) ? wq : (which == 1) ? wk : (which == 2) ? wv : wo;
  bf16_t* dst = (which < 3) ? wqkv_t : wo_t;
  int noff = (which < 3) ? which * 1024 : 0;
  __shared__ float tile[64][65];
  int tr = blockIdx.y, tc = blockIdx.x;
  int t = threadIdx.x;
#pragma unroll
  for (int p = 0; p < 4; ++p) {
    int e = (p * 256 + t) * 4;
    int r = e >> 6, c = e & 63;
    float4 v = *(const float4*)&src[(size_t)(tr * 64 + r) * 1024 + tc * 64 + c];
    tile[r][c] = v.x; tile[r][c + 1] = v.y; tile[r][c + 2] = v.z; tile[r][c + 3] = v.w;
  }
  __syncthreads();
#pragma unroll
  for (int p = 0; p < 4; ++p) {
    int e = (p * 256 + t) * 4;
    int r = e >> 6, c = e & 63;
    union { bf16_t h[4]; uint2 u; } o;
#pragma unroll
    for (int j = 0; j < 4; ++j) o.h[j] = (bf16_t)tile[c + j][r];
    *(uint2*)&dst[(size_t)(noff + tc * 64 + r) * 1024 + tr * 64 + c] = o.u;
  }
}

// ---------------- bias+mask -> bf16 exp2-arg, q-major [b][q][k] ----------------
__global__ void prep_biasmask(const float* __restrict__ bias, const int* __restrict__ mask,
                              bf16_t* __restrict__ bmq) {
  int i = blockIdx.x * blockDim.x + threadIdx.x;  // 8 elements per thread
  float4 b0 = ((const float4*)bias)[i * 2];
  float4 b1 = ((const float4*)bias)[i * 2 + 1];
  int4 m0 = ((const int4*)mask)[i * 2];
  int4 m1 = ((const int4*)mask)[i * 2 + 1];
  union { bf16_t h[8]; uint4 u; } o;
  o.h[0] = (bf16_t)(m0.x ? b0.x * LOG2E - 8.0f : -2.0e38f);
  o.h[1] = (bf16_t)(m0.y ? b0.y * LOG2E - 8.0f : -2.0e38f);
  o.h[2] = (bf16_t)(m0.z ? b0.z * LOG2E - 8.0f : -2.0e38f);
  o.h[3] = (bf16_t)(m0.w ? b0.w * LOG2E - 8.0f : -2.0e38f);
  o.h[4] = (bf16_t)(m1.x ? b1.x * LOG2E - 8.0f : -2.0e38f);
  o.h[5] = (bf16_t)(m1.y ? b1.y * LOG2E - 8.0f : -2.0e38f);
  o.h[6] = (bf16_t)(m1.z ? b1.z * LOG2E - 8.0f : -2.0e38f);
  o.h[7] = (bf16_t)(m1.w ? b1.w * LOG2E - 8.0f : -2.0e38f);
  ((uint4*)bmq)[i] = o.u;
}

// ---------------- V: +bias, f16, transposed to [b,h][e][s] ----------------
__global__ void vt_relayout(const bf16_t* __restrict__ Cqkv, const float* __restrict__ bv,
                            f16_t* __restrict__ vt) {
  __shared__ float tile[64][65];
  int st = blockIdx.x, h = blockIdx.y, b = blockIdx.z;
  int t = threadIdx.x;
#pragma unroll
  for (int p = 0; p < 2; ++p) {
    int e = (p * 256 + t) * 8;
    int r = e >> 6, c = e & 63;  // r = s-local, c = e-local
    bf16x8 v8 = *(const bf16x8*)&Cqkv[(size_t)(b * SS + st * 64 + r) * 3072 + 2048 + h * 64 + c];
#pragma unroll
    for (int j = 0; j < 8; ++j) tile[r][c + j] = (float)v8[j] + bv[h * 64 + c + j];
  }
  __syncthreads();
#pragma unroll
  for (int p = 0; p < 2; ++p) {
    int e = (p * 256 + t) * 8;
    int r = e >> 6, c = e & 63;  // r = e-row, c = s-col
    union { f16_t h[8]; uint4 u; } o;
#pragma unroll
    for (int j = 0; j < 8; ++j) o.h[j] = (f16_t)tile[c + j][r];
    *(uint4*)&vt[(size_t)((b * HH + h) * HDIM + r) * SS + st * 64 + c] = o.u;
  }
}

// ---------------- GEMM (m97 structure): C[M,N] = A[M,K] * Bt[N,K]^T ----------------
// BK=32, unpadded [128][32] LDS tiles, global_load_lds width-16 staging.
template <bool OUT_F32>
__global__ __launch_bounds__(256) void gemm_bt(const bf16_t* __restrict__ A,
                                               const bf16_t* __restrict__ Bt,
                                               bf16_t* __restrict__ Cb, float* __restrict__ Cf,
                                               const float* __restrict__ bias, int M, int N,
                                               int Kd) {
  __shared__ __align__(16) bf16_t As[128][32];
  __shared__ __align__(16) bf16_t Bs[128][32];
  int tid = threadIdx.x;
  int lane = tid & 63, w = tid >> 6;
  int lo = lane & 15, quad = lane >> 4;
  int wm = w >> 1, wn = w & 1;
  int m0 = blockIdx.y * 128, n0 = blockIdx.x * 128;
  int srow = lane >> 2;          // 0..15: row within a 16-row stripe
  int scol = (lane & 3) * 8;     // 16B chunk within the 64B row
  f32x4 acc[4][4] = {};
  for (int kk = 0; kk < Kd; kk += 32) {
#pragma unroll
    for (int t = 0; t < 2; ++t) {
      int rb = (w * 2 + t) * 16;  // wave-uniform stripe base row
      glds16(&A[(size_t)(m0 + rb + srow) * Kd + kk + scol], &As[rb][0]);
      glds16(&Bt[(size_t)(n0 + rb + srow) * Kd + kk + scol], &Bs[rb][0]);
    }
    asm volatile("s_waitcnt vmcnt(0)" ::: "memory");
    __syncthreads();
    bf16x8 am[4], bn[4];
#pragma unroll
    for (int i = 0; i < 4; ++i) am[i] = *(const bf16x8*)&As[wm * 64 + i * 16 + lo][quad * 8];
#pragma unroll
    for (int i = 0; i < 4; ++i) bn[i] = *(const bf16x8*)&Bs[wn * 64 + i * 16 + lo][quad * 8];
#pragma unroll
    for (int mi = 0; mi < 4; ++mi)
#pragma unroll
      for (int ni = 0; ni < 4; ++ni)
        acc[mi][ni] = __builtin_amdgcn_mfma_f32_16x16x32_bf16(am[mi], bn[ni], acc[mi][ni], 0, 0, 0);
    __syncthreads();
  }
#pragma unroll
  for (int mi = 0; mi < 4; ++mi) {
#pragma unroll
    for (int ni = 0; ni < 4; ++ni) {
#pragma unroll
      for (int r = 0; r < 4; ++r) {
        int row = m0 + wm * 64 + mi * 16 + quad * 4 + r;
        int col = n0 + wn * 64 + ni * 16 + lo;
        float v = acc[mi][ni][r];
        if (OUT_F32)
          Cf[(size_t)row * N + col] = v + bias[col];
        else
          Cb[(size_t)row * N + col] = (bf16_t)v;
      }
    }
  }
}

// ---------------- per-head LayerNorm (q,k) + relayout to [B,H,S,HD] bf16 ----------------
__global__ void ln_relayout(const bf16_t* __restrict__ Cqkv, const float* __restrict__ bq,
                            const float* __restrict__ bk, const float* __restrict__ q_scale,
                            const float* __restrict__ k_scale, bf16_t* __restrict__ qb,
                            bf16_t* __restrict__ kb) {
  int mode = blockIdx.y;  // 0=q,1=k
  int vec = blockIdx.x * 4 + (threadIdx.x >> 6);
  int lane = threadIdx.x & 63;
  int bs = vec >> 4, h = vec & 15;
  int b = bs >> 11, s = bs & 2047;
  const float* badd = (mode == 0) ? bq : bk;
  float x = (float)Cqkv[(size_t)bs * 3072 + mode * 1024 + h * 64 + lane] + badd[h * 64 + lane];
  float sum = x;
#pragma unroll
  for (int off = 32; off >= 1; off >>= 1) sum += __shfl_xor(sum, off, 64);
  float mean = sum * (1.0f / 64.0f);
  float d = x - mean;
  float vs = d * d;
#pragma unroll
  for (int off = 32; off >= 1; off >>= 1) vs += __shfl_xor(vs, off, 64);
  float var = vs * (1.0f / 64.0f);
  const float* sc = (mode == 0) ? q_scale : k_scale;
  float y = d * rsqrtf(var + 1e-6f) * sc[lane];
  if (mode == 0) y *= 0.125f * LOG2E;  // 1/sqrt(HD) * log2(e): attn uses raw exp2
  bf16_t* dst = (mode == 0) ? qb : kb;
  dst[(size_t)((b * 16 + h) * 2048 + s) * 64 + lane] = (bf16_t)y;
}

// ---------------- flash attention: 512 threads, 8 waves x 16 q, register-resident P ----------------
// Block: 128 q rows of one (b,h). Per 64-k tile:
//   stage K[64k][64e] bf16, V^T[64e][64k] f16, Bm[128q][64k] bf16 into LDS (coalesced b128)
//   S^T = K·Q^T + bm   (x32 bf16 MFMA; A=K frag, B=Q^T frag, C init = biasmask)
//   P^T = exp2(S^T)    -- C-layout regs (k=quad*4+r, q=lo) == x16 B-operand layout
//   O^T += V^T·P^T     (x16 f16 MFMA; A=V^T frag from LDS)   [P never leaves regs]
//   l   += ones·P^T    (x16 f16 MFMA; replicated across rows)
__global__ __launch_bounds__(512) void attn_kernel(const bf16_t* __restrict__ qb,
                                                   const bf16_t* __restrict__ kb,
                                                   const f16_t* __restrict__ vt,
                                                   const bf16_t* __restrict__ bmq,
                                                   bf16_t* __restrict__ xout) {
  __shared__ __align__(16) bf16_t Ks[64][72];   // [k][e]
  __shared__ __align__(16) f16_t Vs[64][72];    // [e][k]
  __shared__ __align__(16) bf16_t Bm[128][72];  // [q][k]
  int tid = threadIdx.x;
  int lane = tid & 63, w = tid >> 6;  // w: 0..7
  int lo = lane & 15, quad = lane >> 4;
  int qt = blockIdx.x, h = blockIdx.y, b = blockIdx.z;
  size_t headoff = (size_t)(b * HH + h) * SS * HDIM;
  int q0b = qt * 128;           // block q base
  int qw = q0b + w * 16;        // wave q base (16 q rows per wave)
  const bf16_t* kbase = kb + headoff;
  const f16_t* vbase = vt + headoff;
  const bf16_t* bmbase = bmq + (size_t)b * SS * SS;

  // Q^T B-frags (x32): B[e][q], q=lo, e=ec*32+quad*8+j  (one-time global gather)
  bf16x8 bqf[2];
#pragma unroll
  for (int ec = 0; ec < 2; ++ec)
    bqf[ec] = *(const bf16x8*)&qb[headoff + (size_t)(qw + lo) * HDIM + ec * 32 + quad * 8];

  f16x4 ones;
#pragma unroll
  for (int j = 0; j < 4; ++j) ones[j] = (f16_t)1.0f;

  f32x4 ot[4] = {};  // [eb]  O^T: row=e-local(quad*4+r), col=q(lo)
  f32x4 lacc = {};

  // staging indices (512 threads)
  int sr = tid >> 3;            // 0..63
  int sc8 = (tid & 7) * 8;      // 0..56

  for (int kt = 0; kt < SS / 64; ++kt) {
    int k0 = kt * 64;
    *(uint4*)&Ks[sr][sc8] = *(const uint4*)&kbase[(size_t)(k0 + sr) * HDIM + sc8];
    *(uint4*)&Vs[sr][sc8] = *(const uint4*)&vbase[(size_t)sr * SS + k0 + sc8];
#pragma unroll
    for (int p = 0; p < 2; ++p) {
      int idx = (p * 512 + tid) * 8;
      int r = idx >> 6, c = idx & 63;  // r = q-local 0..127
      *(uint4*)&Bm[r][c] = *(const uint4*)&bmbase[(size_t)(q0b + r) * SS + k0 + c];
    }
    __syncthreads();

    // K A-frags
    bf16x8 ka[4][2];
#pragma unroll
    for (int mb = 0; mb < 4; ++mb)
#pragma unroll
      for (int ec = 0; ec < 2; ++ec)
        ka[mb][ec] = *(const bf16x8*)&Ks[mb * 16 + lo][ec * 32 + quad * 8];

    // S^T = K·Q^T + bm ; P^T = exp2
    f16x4 pf[4];
#pragma unroll
    for (int mb = 0; mb < 4; ++mb) {
      bf16x4 bm4 = *(const bf16x4*)&Bm[w * 16 + lo][mb * 16 + quad * 4];
      f32x4 s;
#pragma unroll
      for (int r = 0; r < 4; ++r) s[r] = (float)bm4[r];
      s = __builtin_amdgcn_mfma_f32_16x16x32_bf16(ka[mb][0], bqf[0], s, 0, 0, 0);
      s = __builtin_amdgcn_mfma_f32_16x16x32_bf16(ka[mb][1], bqf[1], s, 0, 0, 0);
#pragma unroll
      for (int r = 0; r < 4; ++r) pf[mb][r] = (f16_t)__builtin_amdgcn_exp2f(s[r]);
    }

    // O^T += V^T·P^T ; l += ones·P^T
#pragma unroll
    for (int mb = 0; mb < 4; ++mb) {
#pragma unroll
      for (int eb = 0; eb < 4; ++eb) {
        f16x4 va = *(const f16x4*)&Vs[eb * 16 + lo][mb * 16 + quad * 4];
        ot[eb] = __builtin_amdgcn_mfma_f32_16x16x16f16(va, pf[mb], ot[eb], 0, 0, 0);
      }
      lacc = __builtin_amdgcn_mfma_f32_16x16x16f16(ones, pf[mb], lacc, 0, 0, 0);
    }
    __syncthreads();
  }

  // epilogue: O = O^T / l; lane covers e = eb*16 + quad*4 + r, q = qw + lo
  float rl = 1.0f / lacc[0];
  int q = qw + lo;
#pragma unroll
  for (int eb = 0; eb < 4; ++eb) {
    union { bf16_t h4[4]; uint2 u; } o;
#pragma unroll
    for (int r = 0; r < 4; ++r) o.h4[r] = (bf16_t)(ot[eb][r] * rl);
    *(uint2*)&xout[(size_t)(b * SS + q) * DD + h * 64 + eb * 16 + quad * 4] = o.u;
  }
}

extern "C" void kernel_launch(void* const* d_in, const int* in_sizes, int n_in, void* d_out,
                              int out_size, void* d_ws, size_t ws_size, hipStream_t stream) {
  const float* inputs_q = (const float*)d_in[0];
  const float* bias = (const float*)d_in[1];
  const int* mask = (const int*)d_in[2];
  const float* wq = (const float*)d_in[3];
  const float* bq = (const float*)d_in[4];
  const float* wk = (const float*)d_in[5];
  const float* bk = (const float*)d_in[6];
  const float* wv = (const float*)d_in[7];
  const float* bv = (const float*)d_in[8];
  const float* q_scale = (const float*)d_in[9];
  const float* k_scale = (const float*)d_in[10];
  const float* wo = (const float*)d_in[11];
  const float* bo = (const float*)d_in[12];
  float* out = (float*)d_out;

  char* ws = (char*)d_ws;
  bf16_t* xb     = (bf16_t*)(ws);                        //  8 MB  [4096][1024]
  bf16_t* wqkv_t = (bf16_t*)(ws + ((size_t)8 << 20));    //  6 MB  [3072][1024]
  bf16_t* wo_t   = (bf16_t*)(ws + ((size_t)14 << 20));   //  2 MB  [1024][1024]
  bf16_t* cqkv   = (bf16_t*)(ws + ((size_t)16 << 20));   // 24 MB  [4096][3072]  (dead after ln/vt)
  bf16_t* bmq    = (bf16_t*)(ws + ((size_t)16 << 20));   // 17 MB  [B][2048q][2048k] (overlaps cqkv)
  bf16_t* qb2    = (bf16_t*)(ws + ((size_t)40 << 20));   //  8 MB  [B,H,S,64]
  bf16_t* kb2    = (bf16_t*)(ws + ((size_t)48 << 20));   //  8 MB
  f16_t*  vtb    = (f16_t*)(ws + ((size_t)56 << 20));    //  8 MB  [B,H,64,S] f16
  bf16_t* xattn  = (bf16_t*)(ws + ((size_t)64 << 20));   //  8 MB  [4096][1024]

  convert_x<<<(BS * DD / 4 + 255) / 256, 256, 0, stream>>>(inputs_q, xb, BS * DD / 4);
  transpose_convert<<<dim3(16, 16, 4), 256, 0, stream>>>(wq, wk, wv, wo, wqkv_t, wo_t);
  gemm_bt<false><<<dim3(24, 32), 256, 0, stream>>>(xb, wqkv_t, cqkv, nullptr, nullptr, BS, 3072, DD);
  ln_relayout<<<dim3(BS * HH / 4, 2), 256, 0, stream>>>(cqkv, bq, bk, q_scale, k_scale, qb2, kb2);
  vt_relayout<<<dim3(32, 16, 2), 256, 0, stream>>>(cqkv, bv, vtb);
  prep_biasmask<<<BB * SS * SS / 8 / 256, 256, 0, stream>>>(bias, mask, bmq);  // after cqkv consumed
  attn_kernel<<<dim3(SS / 128, HH, BB), 512, 0, stream>>>(qb2, kb2, vtb, bmq, xattn);
  gemm_bt<true><<<dim3(8, 32), 256, 0, stream>>>(xattn, wo_t, nullptr, out, bo, BS, 1024, DD);
}

// Round 8
// 300.714 us; speedup vs baseline: 1.0328x; 1.0328x over previous
//
#include <hip/hip_runtime.h>
#include <cstdint>
#include <cstddef>

typedef __bf16 bf16_t;
typedef __bf16 bf16x8 __attribute__((ext_vector_type(8)));
typedef __bf16 bf16x4 __attribute__((ext_vector_type(4)));
typedef _Float16 f16_t;
typedef _Float16 f16x4 __attribute__((ext_vector_type(4)));
typedef float f32x4 __attribute__((ext_vector_type(4)));

constexpr int BB = 2, SS = 2048, DD = 1024, HH = 16, HDIM = 64;
constexpr int BS = BB * SS;  // 4096
constexpr float LOG2E = 1.4426950408889634f;

// async global->LDS, 16B per lane; LDS dest is wave-uniform base + lane*16
__device__ __forceinline__ void glds16(const void* g, void* l) {
  __builtin_amdgcn_global_load_lds((const __attribute__((address_space(1))) void*)g,
                                   (__attribute__((address_space(3))) void*)l, 16, 0, 0);
}

// ---------------- fused input prep: convert_x | weight transposes | bias+mask ----------------
// blocks [0,4096):        x fp32 -> bf16 (4 float4 / thread-block pattern)
// blocks [4096,5120):     wq/wk/wv/wo 64x64 tile transpose+convert
// blocks [5120,9216):     bias+mask -> bf16 exp2-arg, q-major
__global__ __launch_bounds__(256) void prep_fused(
    const float* __restrict__ x, const float* __restrict__ wq, const float* __restrict__ wk,
    const float* __restrict__ wv, const float* __restrict__ wo, const float* __restrict__ bias,
    const int* __restrict__ mask, bf16_t* __restrict__ xb, bf16_t* __restrict__ wqkv_t,
    bf16_t* __restrict__ wo_t, bf16_t* __restrict__ bmq) {
  __shared__ float tile[64][65];
  int bid = blockIdx.x;
  int t = threadIdx.x;
  if (bid < 4096) {
    int i = bid * 256 + t;
    float4 v = ((const float4*)x)[i];
    union { bf16_t h[4]; uint2 u; } o;
    o.h[0] = (bf16_t)v.x; o.h[1] = (bf16_t)v.y; o.h[2] = (bf16_t)v.z; o.h[3] = (bf16_t)v.w;
    ((uint2*)xb)[i] = o.u;
  } else if (bid < 5120) {
    int id = bid - 4096;
    int which = id >> 8, tr = (id >> 4) & 15, tc = id & 15;
    const float* src = (which == 0) ? wq : (which == 1) ? wk : (which == 2) ? wv : wo;
    bf16_t* dst = (which < 3) ? wqkv_t : wo_t;
    int noff = (which < 3) ? which * 1024 : 0;
#pragma unroll
    for (int p = 0; p < 4; ++p) {
      int e = (p * 256 + t) * 4;
      int r = e >> 6, c = e & 63;
      float4 v = *(const float4*)&src[(size_t)(tr * 64 + r) * 1024 + tc * 64 + c];
      tile[r][c] = v.x; tile[r][c + 1] = v.y; tile[r][c + 2] = v.z; tile[r][c + 3] = v.w;
    }
    __syncthreads();
#pragma unroll
    for (int p = 0; p < 4; ++p) {
      int e = (p * 256 + t) * 4;
      int r = e >> 6, c = e & 63;
      union { bf16_t h[4]; uint2 u; } o;
#pragma unroll
      for (int j = 0; j < 4; ++j) o.h[j] = (bf16_t)tile[c + j][r];
      *(uint2*)&dst[(size_t)(noff + tc * 64 + r) * 1024 + tr * 64 + c] = o.u;
    }
  } else {
    int i = (bid - 5120) * 256 + t;  // 8 elements per thread
    float4 b0 = ((const float4*)bias)[i * 2];
    float4 b1 = ((const float4*)bias)[i * 2 + 1];
    int4 m0 = ((const int4*)mask)[i * 2];
    int4 m1 = ((const int4*)mask)[i * 2 + 1];
    union { bf16_t h[8]; uint4 u; } o;
    o.h[0] = (bf16_t)(m0.x ? b0.x * LOG2E - 8.0f : -2.0e38f);
    o.h[1] = (bf16_t)(m0.y ? b0.y * LOG2E - 8.0f : -2.0e38f);
    o.h[2] = (bf16_t)(m0.z ? b0.z * LOG2E - 8.0f : -2.0e38f);
    o.h[3] = (bf16_t)(m0.w ? b0.w * LOG2E - 8.0f : -2.0e38f);
    o.h[4] = (bf16_t)(m1.x ? b1.x * LOG2E - 8.0f : -2.0e38f);
    o.h[5] = (bf16_t)(m1.y ? b1.y * LOG2E - 8.0f : -2.0e38f);
    o.h[6] = (bf16_t)(m1.z ? b1.z * LOG2E - 8.0f : -2.0e38f);
    o.h[7] = (bf16_t)(m1.w ? b1.w * LOG2E - 8.0f : -2.0e38f);
    ((uint4*)bmq)[i] = o.u;
  }
}

// ---------------- GEMM (m97 structure): C[M,N] = A[M,K] * Bt[N,K]^T ----------------
template <bool OUT_F32>
__global__ __launch_bounds__(256) void gemm_bt(const bf16_t* __restrict__ A,
                                               const bf16_t* __restrict__ Bt,
                                               bf16_t* __restrict__ Cb, float* __restrict__ Cf,
                                               const float* __restrict__ bias, int M, int N,
                                               int Kd) {
  __shared__ __align__(16) bf16_t As[128][32];
  __shared__ __align__(16) bf16_t Bs[128][32];
  int tid = threadIdx.x;
  int lane = tid & 63, w = tid >> 6;
  int lo = lane & 15, quad = lane >> 4;
  int wm = w >> 1, wn = w & 1;
  int m0 = blockIdx.y * 128, n0 = blockIdx.x * 128;
  int srow = lane >> 2;
  int scol = (lane & 3) * 8;
  f32x4 acc[4][4] = {};
  for (int kk = 0; kk < Kd; kk += 32) {
#pragma unroll
    for (int t = 0; t < 2; ++t) {
      int rb = (w * 2 + t) * 16;
      glds16(&A[(size_t)(m0 + rb + srow) * Kd + kk + scol], &As[rb][0]);
      glds16(&Bt[(size_t)(n0 + rb + srow) * Kd + kk + scol], &Bs[rb][0]);
    }
    asm volatile("s_waitcnt vmcnt(0)" ::: "memory");
    __syncthreads();
    bf16x8 am[4], bn[4];
#pragma unroll
    for (int i = 0; i < 4; ++i) am[i] = *(const bf16x8*)&As[wm * 64 + i * 16 + lo][quad * 8];
#pragma unroll
    for (int i = 0; i < 4; ++i) bn[i] = *(const bf16x8*)&Bs[wn * 64 + i * 16 + lo][quad * 8];
#pragma unroll
    for (int mi = 0; mi < 4; ++mi)
#pragma unroll
      for (int ni = 0; ni < 4; ++ni)
        acc[mi][ni] = __builtin_amdgcn_mfma_f32_16x16x32_bf16(am[mi], bn[ni], acc[mi][ni], 0, 0, 0);
    __syncthreads();
  }
#pragma unroll
  for (int mi = 0; mi < 4; ++mi) {
#pragma unroll
    for (int ni = 0; ni < 4; ++ni) {
#pragma unroll
      for (int r = 0; r < 4; ++r) {
        int row = m0 + wm * 64 + mi * 16 + quad * 4 + r;
        int col = n0 + wn * 64 + ni * 16 + lo;
        float v = acc[mi][ni][r];
        if (OUT_F32)
          Cf[(size_t)row * N + col] = v + bias[col];
        else
          Cb[(size_t)row * N + col] = (bf16_t)v;
      }
    }
  }
}

// ---------------- fused post-QKV: LN(q,k)+relayout | V transpose ----------------
// blocks [0,16384):       q LN -> qb  (mode 0)
// blocks [16384,32768):   k LN -> kb  (mode 1)
// blocks [32768,33792):   v +bias, f16, transpose -> vt
__global__ __launch_bounds__(256) void postqkv(const bf16_t* __restrict__ Cqkv,
                                               const float* __restrict__ bq,
                                               const float* __restrict__ bk,
                                               const float* __restrict__ bv,
                                               const float* __restrict__ q_scale,
                                               const float* __restrict__ k_scale,
                                               bf16_t* __restrict__ qb, bf16_t* __restrict__ kb,
                                               f16_t* __restrict__ vt) {
  __shared__ float tile[64][65];
  int bid = blockIdx.x;
  int t = threadIdx.x;
  if (bid < 32768) {
    int mode = bid >> 14;  // 0=q,1=k
    int vec = (bid & 16383) * 4 + (t >> 6);
    int lane = t & 63;
    int bs = vec >> 4, h = vec & 15;
    int b = bs >> 11, s = bs & 2047;
    const float* badd = (mode == 0) ? bq : bk;
    float x = (float)Cqkv[(size_t)bs * 3072 + mode * 1024 + h * 64 + lane] + badd[h * 64 + lane];
    float sum = x;
#pragma unroll
    for (int off = 32; off >= 1; off >>= 1) sum += __shfl_xor(sum, off, 64);
    float mean = sum * (1.0f / 64.0f);
    float d = x - mean;
    float vs = d * d;
#pragma unroll
    for (int off = 32; off >= 1; off >>= 1) vs += __shfl_xor(vs, off, 64);
    float var = vs * (1.0f / 64.0f);
    const float* sc = (mode == 0) ? q_scale : k_scale;
    float y = d * rsqrtf(var + 1e-6f) * sc[lane];
    if (mode == 0) y *= 0.125f * LOG2E;  // 1/sqrt(HD) * log2(e): attn uses raw exp2
    bf16_t* dst = (mode == 0) ? qb : kb;
    dst[(size_t)((b * 16 + h) * 2048 + s) * 64 + lane] = (bf16_t)y;
  } else {
    int id2 = bid - 32768;
    int st = id2 & 31, h = (id2 >> 5) & 15, b = id2 >> 9;
#pragma unroll
    for (int p = 0; p < 2; ++p) {
      int e = (p * 256 + t) * 8;
      int r = e >> 6, c = e & 63;  // r = s-local, c = e-local
      bf16x8 v8 = *(const bf16x8*)&Cqkv[(size_t)(b * SS + st * 64 + r) * 3072 + 2048 + h * 64 + c];
#pragma unroll
      for (int j = 0; j < 8; ++j) tile[r][c + j] = (float)v8[j] + bv[h * 64 + c + j];
    }
    __syncthreads();
#pragma unroll
    for (int p = 0; p < 2; ++p) {
      int e = (p * 256 + t) * 8;
      int r = e >> 6, c = e & 63;  // r = e-row, c = s-col
      union { f16_t h[8]; uint4 u; } o;
#pragma unroll
      for (int j = 0; j < 8; ++j) o.h[j] = (f16_t)tile[c + j][r];
      *(uint4*)&vt[(size_t)((b * HH + h) * HDIM + r) * SS + st * 64 + c] = o.u;
    }
  }
}

// ---------------- flash attention (R6 best): 256 thr, 4 waves x 32 q, register-resident P ----------------
__global__ __launch_bounds__(256) void attn_kernel(const bf16_t* __restrict__ qb,
                                                   const bf16_t* __restrict__ kb,
                                                   const f16_t* __restrict__ vt,
                                                   const bf16_t* __restrict__ bmq,
                                                   bf16_t* __restrict__ xout) {
  __shared__ __align__(16) bf16_t Ks[64][72];   // [k][e]
  __shared__ __align__(16) f16_t Vs[64][72];    // [e][k]
  __shared__ __align__(16) bf16_t Bm[128][72];  // [q][k]
  int tid = threadIdx.x;
  int lane = tid & 63, w = tid >> 6;
  int lo = lane & 15, quad = lane >> 4;
  int qt = blockIdx.x, h = blockIdx.y, b = blockIdx.z;
  size_t headoff = (size_t)(b * HH + h) * SS * HDIM;
  int q0b = qt * 128;
  int q0 = q0b + w * 32;
  const bf16_t* kbase = kb + headoff;
  const f16_t* vbase = vt + headoff;
  const bf16_t* bmbase = bmq + (size_t)b * SS * SS;

  bf16x8 bqf[2][2];
#pragma unroll
  for (int qg = 0; qg < 2; ++qg)
#pragma unroll
    for (int ec = 0; ec < 2; ++ec)
      bqf[qg][ec] =
          *(const bf16x8*)&qb[headoff + (size_t)(q0 + qg * 16 + lo) * HDIM + ec * 32 + quad * 8];

  f16x4 ones;
#pragma unroll
  for (int j = 0; j < 4; ++j) ones[j] = (f16_t)1.0f;

  f32x4 ot[2][4] = {};
  f32x4 lacc[2] = {};

  for (int kt = 0; kt < SS / 64; ++kt) {
    int k0 = kt * 64;
#pragma unroll
    for (int p = 0; p < 2; ++p) {
      int idx = (p * 256 + tid) * 8;
      int r = idx >> 6, c = idx & 63;
      *(uint4*)&Ks[r][c] = *(const uint4*)&kbase[(size_t)(k0 + r) * HDIM + c];
      *(uint4*)&Vs[r][c] = *(const uint4*)&vbase[(size_t)r * SS + k0 + c];
    }
#pragma unroll
    for (int p = 0; p < 4; ++p) {
      int idx = (p * 256 + tid) * 8;
      int r = idx >> 6, c = idx & 63;
      *(uint4*)&Bm[r][c] = *(const uint4*)&bmbase[(size_t)(q0b + r) * SS + k0 + c];
    }
    __syncthreads();

    bf16x8 ka[4][2];
#pragma unroll
    for (int mb = 0; mb < 4; ++mb)
#pragma unroll
      for (int ec = 0; ec < 2; ++ec)
        ka[mb][ec] = *(const bf16x8*)&Ks[mb * 16 + lo][ec * 32 + quad * 8];

    f16x4 pf[2][4];
#pragma unroll
    for (int qg = 0; qg < 2; ++qg) {
#pragma unroll
      for (int mb = 0; mb < 4; ++mb) {
        bf16x4 bm4 = *(const bf16x4*)&Bm[w * 32 + qg * 16 + lo][mb * 16 + quad * 4];
        f32x4 s;
#pragma unroll
        for (int r = 0; r < 4; ++r) s[r] = (float)bm4[r];
        s = __builtin_amdgcn_mfma_f32_16x16x32_bf16(ka[mb][0], bqf[qg][0], s, 0, 0, 0);
        s = __builtin_amdgcn_mfma_f32_16x16x32_bf16(ka[mb][1], bqf[qg][1], s, 0, 0, 0);
#pragma unroll
        for (int r = 0; r < 4; ++r) pf[qg][mb][r] = (f16_t)__builtin_amdgcn_exp2f(s[r]);
      }
    }

#pragma unroll
    for (int mb = 0; mb < 4; ++mb) {
#pragma unroll
      for (int eb = 0; eb < 4; ++eb) {
        f16x4 va = *(const f16x4*)&Vs[eb * 16 + lo][mb * 16 + quad * 4];
#pragma unroll
        for (int qg = 0; qg < 2; ++qg)
          ot[qg][eb] = __builtin_amdgcn_mfma_f32_16x16x16f16(va, pf[qg][mb], ot[qg][eb], 0, 0, 0);
      }
#pragma unroll
      for (int qg = 0; qg < 2; ++qg)
        lacc[qg] = __builtin_amdgcn_mfma_f32_16x16x16f16(ones, pf[qg][mb], lacc[qg], 0, 0, 0);
    }
    __syncthreads();
  }

#pragma unroll
  for (int qg = 0; qg < 2; ++qg) {
    float rl = 1.0f / lacc[qg][0];
    int q = q0 + qg * 16 + lo;
#pragma unroll
    for (int eb = 0; eb < 4; ++eb) {
      union { bf16_t h4[4]; uint2 u; } o;
#pragma unroll
      for (int r = 0; r < 4; ++r) o.h4[r] = (bf16_t)(ot[qg][eb][r] * rl);
      *(uint2*)&xout[(size_t)(b * SS + q) * DD + h * 64 + eb * 16 + quad * 4] = o.u;
    }
  }
}

extern "C" void kernel_launch(void* const* d_in, const int* in_sizes, int n_in, void* d_out,
                              int out_size, void* d_ws, size_t ws_size, hipStream_t stream) {
  const float* inputs_q = (const float*)d_in[0];
  const float* bias = (const float*)d_in[1];
  const int* mask = (const int*)d_in[2];
  const float* wq = (const float*)d_in[3];
  const float* bq = (const float*)d_in[4];
  const float* wk = (const float*)d_in[5];
  const float* bk = (const float*)d_in[6];
  const float* wv = (const float*)d_in[7];
  const float* bv = (const float*)d_in[8];
  const float* q_scale = (const float*)d_in[9];
  const float* k_scale = (const float*)d_in[10];
  const float* wo = (const float*)d_in[11];
  const float* bo = (const float*)d_in[12];
  float* out = (float*)d_out;

  // ws packing (67 MB; overlaps only between dead/live pairs):
  //   wo_t   0-2    (live to end)
  //   bmq    2-19   (live prep -> attn)
  //   cqkv   19-43  (live gemm_qkv -> postqkv)   xattn 19-27 (overlap; live attn -> gemm_out)
  //   xb     43-51  (live prep -> gemm_qkv)      qb2  43-51 (overlap; live postqkv -> attn)
  //   wqkv_t 51-57  (live prep -> gemm_qkv)      kb2  51-59 (overlap; live postqkv -> attn)
  //   vtb    59-67  (live postqkv -> attn)
  char* ws = (char*)d_ws;
  bf16_t* wo_t   = (bf16_t*)(ws);
  bf16_t* bmq    = (bf16_t*)(ws + ((size_t)2 << 20));
  bf16_t* cqkv   = (bf16_t*)(ws + ((size_t)19 << 20));
  bf16_t* xattn  = (bf16_t*)(ws + ((size_t)19 << 20));
  bf16_t* xb     = (bf16_t*)(ws + ((size_t)43 << 20));
  bf16_t* qb2    = (bf16_t*)(ws + ((size_t)43 << 20));
  bf16_t* wqkv_t = (bf16_t*)(ws + ((size_t)51 << 20));
  bf16_t* kb2    = (bf16_t*)(ws + ((size_t)51 << 20));
  f16_t*  vtb    = (f16_t*)(ws + ((size_t)59 << 20));

  prep_fused<<<9216, 256, 0, stream>>>(inputs_q, wq, wk, wv, wo, bias, mask, xb, wqkv_t, wo_t, bmq);
  gemm_bt<false><<<dim3(24, 32), 256, 0, stream>>>(xb, wqkv_t, cqkv, nullptr, nullptr, BS, 3072, DD);
  postqkv<<<33792, 256, 0, stream>>>(cqkv, bq, bk, bv, q_scale, k_scale, qb2, kb2, vtb);
  attn_kernel<<<dim3(SS / 128, HH, BB), 256, 0, stream>>>(qb2, kb2, vtb, bmq, xattn);
  gemm_bt<true><<<dim3(8, 32), 256, 0, stream>>>(xattn, wo_t, nullptr, out, bo, BS, 1024, DD);
}